// Round 10
// baseline (1241.675 us; speedup 1.0000x reference)
//
#include <hip/hip_runtime.h>
#include <stdint.h>

#define NN 50000   // nodes
#define NE 800000  // edges
#define HD 128     // hidden
#define NL 4       // layers
#define NM 64      // nodes per block (node kernel)
#define EB 128     // edges per block (edge kernel)
#define SCH ((NN + 1023) / 1024)   // scan chunk per thread (49)

typedef __bf16 bf16x8 __attribute__((ext_vector_type(8)));
typedef __bf16 bf16x4 __attribute__((ext_vector_type(4)));
typedef float  f32x4  __attribute__((ext_vector_type(4)));

__device__ __forceinline__ f32x4 mfma16(bf16x8 a, bf16x8 b, f32x4 c) {
  return __builtin_amdgcn_mfma_f32_16x16x32_bf16(a, b, c, 0, 0, 0);
}

template<int MT, int NT>
__device__ __forceinline__ void zero_acc(f32x4 (&acc)[MT][NT]) {
#pragma unroll
  for (int i = 0; i < MT; ++i)
#pragma unroll
    for (int j = 0; j < NT; ++j) acc[i][j] = f32x4{0.f, 0.f, 0.f, 0.f};
}

// ---------------- generic MT/NT gemm chunk ----------------------------------
template<int MT, int NT, int KS>
__device__ __forceinline__ void gemm_chunk(const __bf16* A, int sa,
    const __bf16* __restrict__ Bt, int Krow, int k0,
    int m_off, int n_off, int lane, f32x4 (&acc)[MT][NT])
{
  const int arow = lane & 15;
  const int quad = lane >> 4;
  bf16x8 b[KS][NT];
#pragma unroll
  for (int ks = 0; ks < KS; ++ks)
#pragma unroll
    for (int nt = 0; nt < NT; ++nt)
      b[ks][nt] = *reinterpret_cast<const bf16x8*>(
          Bt + (size_t)(n_off + nt * 16 + arow) * Krow + k0 + ks * 32 + quad * 8);
#pragma unroll
  for (int ks = 0; ks < KS; ++ks) {
    const int k = k0 + ks * 32 + quad * 8;
    bf16x8 a[MT];
#pragma unroll
    for (int mt = 0; mt < MT; ++mt)
      a[mt] = *reinterpret_cast<const bf16x8*>(A + (m_off + mt * 16 + arow) * sa + k);
#pragma unroll
    for (int mt = 0; mt < MT; ++mt)
#pragma unroll
      for (int nt = 0; nt < NT; ++nt)
        acc[mt][nt] = mfma16(a[mt], b[ks][nt], acc[mt][nt]);
  }
}

// C/D layout (m89-verified): col = lane&15, row = (lane>>4)*4 + reg
template<int MT, int NT, bool RELU>
__device__ __forceinline__ void store_tile(__bf16* O, int so,
    const float* __restrict__ bias, int m_off, int n_off, int lane,
    f32x4 (&acc)[MT][NT])
{
  const int quad = lane >> 4;
  const int cl = lane & 15;
#pragma unroll
  for (int nt = 0; nt < NT; ++nt) {
    const int col = n_off + nt * 16 + cl;
    const float bv = bias[col];
#pragma unroll
    for (int mt = 0; mt < MT; ++mt)
#pragma unroll
      for (int r = 0; r < 4; ++r) {
        const int row = m_off + mt * 16 + quad * 4 + r;
        float v = acc[mt][nt][r] + bv;
        if (RELU) v = fmaxf(v, 0.f);
        O[row * so + col] = (__bf16)v;
      }
  }
}

// ---- prep: W[l][K0][128] fp32 -> Wt[l][128][Kp] bf16 (transposed, zero-pad K)
__global__ void prep_w(const float* __restrict__ W, __bf16* __restrict__ Wt,
                       int K0, int Kp) {
  int idx = blockIdx.x * 256 + threadIdx.x;
  int total = NL * HD * Kp;
  if (idx >= total) return;
  int l = idx / (HD * Kp);
  int rem = idx - l * HD * Kp;
  int n = rem / Kp;
  int k = rem - n * Kp;
  float v = (k < K0) ? W[((size_t)l * K0 + k) * HD + n] : 0.f;
  Wt[idx] = (__bf16)v;
}

// ---- prep P/Q weights: fold rel_mom rows (260:263) into h_col/h_row blocks.
__global__ void prep_pqw(const float* __restrict__ We1,
                         __bf16* __restrict__ Wtopt, __bf16* __restrict__ Wbott) {
  int idx = blockIdx.x * 256 + threadIdx.x;
  if (idx >= NL * HD * HD) return;
  int l = idx / (HD * HD);
  int rem = idx - l * HD * HD;
  int n = rem >> 7;
  int k = rem & 127;
  const float* W = We1 + (size_t)l * 263 * HD;
  float extra = (k >= 3 && k < 6) ? W[(260 + k - 3) * HD + n] : 0.f;
  Wtopt[idx] = (__bf16)(W[k * HD + n] + extra);
  Wbott[idx] = (__bf16)(W[(128 + k) * HD + n] - extra);
}

// ---- h0 = x @ W_in + b_in
__global__ void h0_kernel(const float* __restrict__ x, const float* __restrict__ W,
                          const float* __restrict__ b, float* __restrict__ H32,
                          __bf16* __restrict__ HB) {
  int idx = blockIdx.x * 256 + threadIdx.x;
  if (idx >= NN * HD) return;
  int node = idx >> 7, j = idx & 127;
  const float* xr = x + node * 16;
  float s = b[j];
#pragma unroll
  for (int k = 0; k < 16; ++k) s += xr[k] * W[k * HD + j];
  H32[idx] = s;
  HB[idx] = (__bf16)s;
}

// ---- CSR build (counting sort of edges by col)
__global__ void hist_kernel(const int* __restrict__ ei, int* __restrict__ cnt) {
  int e = blockIdx.x * 256 + threadIdx.x;
  if (e < NE) atomicAdd(&cnt[ei[NE + e]], 1);
}

// ---- chunked single-block scan: thread t owns cnt[t*SCH .. t*SCH+SCH-1].
__global__ void scan_kernel(const int* __restrict__ cnt, int* __restrict__ cur) {
  __shared__ int wsum[16];
  const int t = threadIdx.x;            // 1024 threads
  const int lane = t & 63, wid = t >> 6;
  const int base = t * SCH;
  int s = 0;
  for (int k = 0; k < SCH; ++k) {
    int i = base + k;
    if (i < NN) s += cnt[i];
  }
  int incl = s;
#pragma unroll
  for (int off = 1; off < 64; off <<= 1) {
    int u = __shfl_up(incl, off, 64);
    if (lane >= off) incl += u;
  }
  if (lane == 63) wsum[wid] = incl;
  __syncthreads();
  int woff = 0;
  for (int k = 0; k < wid; ++k) woff += wsum[k];
  int run = woff + incl - s;            // exclusive prefix of this chunk
  for (int k = 0; k < SCH; ++k) {
    int i = base + k;
    if (i < NN) { cur[i] = run; run += cnt[i]; }
  }
}

// ---- scatter + fused dist
__global__ void scatter_kernel(const int* __restrict__ ei, int* __restrict__ cur,
                               const float* __restrict__ pos,
                               int* __restrict__ ROWS, int* __restrict__ COLS,
                               __bf16* __restrict__ DSTb) {
  int e = blockIdx.x * 256 + threadIdx.x;
  if (e < NE) {
    int r = ei[e], c = ei[NE + e];
    int p = atomicAdd(&cur[c], 1);
    ROWS[p] = r;
    COLS[p] = c;
    float dx = pos[c * 3 + 0] - pos[r * 3 + 0];
    float dy = pos[c * 3 + 1] - pos[r * 3 + 1];
    float dz = pos[c * 3 + 2] - pos[r * 3 + 2];
    DSTb[p] = (__bf16)sqrtf(dx * dx + dy * dy + dz * dz);
  }
}

// ---- P/Q kernel v3 (layer 0 ONLY; layers 1-3 fused into node_kernel).
__global__ __launch_bounds__(256, 4) void pq_kernel(
    const __bf16* __restrict__ HB, const float* __restrict__ pos,
    const __bf16* __restrict__ Wtopt, const __bf16* __restrict__ Wbott,
    const float* __restrict__ W4xyz,   // We1_l rows 256..258 : [3][128]
    const float* __restrict__ be1,
    __bf16* __restrict__ PB, __bf16* __restrict__ QB)
{
  __shared__ __bf16 SP[64 * 136];               // 17408 B
  __shared__ __bf16 SQ[64 * 136];               // 17408 B
  const int t = threadIdx.x;
  const int w = t >> 6, lane = t & 63;
  const int g = w & 1;                  // 0 -> P, 1 -> Q
  const int half = w >> 1;              // row half (0/1)
  const int base = blockIdx.x * 64;
  const int rbase = base + half * 32;
  const int arow = lane & 15, quad = lane >> 4, cl = lane & 15;

  const __bf16* Wt = g ? Wbott : Wtopt;
  __bf16* S = (g ? SQ : SP) + half * 32 * 136;

  f32x4 acc[2][8];
  zero_acc(acc);
#pragma unroll
  for (int ks = 0; ks < 4; ++ks) {
    const int k = ks * 32 + quad * 8;
    bf16x8 b[8];
#pragma unroll
    for (int nt = 0; nt < 8; ++nt)
      b[nt] = *reinterpret_cast<const bf16x8*>(Wt + (size_t)(nt * 16 + arow) * HD + k);
    bf16x8 a[2];
#pragma unroll
    for (int mt = 0; mt < 2; ++mt) {
      int row = rbase + mt * 16 + arow;
      if (row >= NN) row = NN - 1;       // clamp (stores guarded)
      a[mt] = *reinterpret_cast<const bf16x8*>(HB + (size_t)row * HD + k);
    }
#pragma unroll
    for (int mt = 0; mt < 2; ++mt)
#pragma unroll
      for (int nt = 0; nt < 8; ++nt)
        acc[mt][nt] = mfma16(a[mt], b[nt], acc[mt][nt]);
  }
  float px[2][4], py[2][4], pz[2][4];
#pragma unroll
  for (int mt = 0; mt < 2; ++mt)
#pragma unroll
    for (int r = 0; r < 4; ++r) {
      int row = rbase + mt * 16 + quad * 4 + r;
      if (row >= NN) row = NN - 1;
      px[mt][r] = pos[row * 3 + 0];
      py[mt][r] = pos[row * 3 + 1];
      pz[mt][r] = pos[row * 3 + 2];
    }
#pragma unroll
  for (int nt = 0; nt < 8; ++nt) {
    const int col = nt * 16 + cl;
    const float w0 = W4xyz[col], w1 = W4xyz[HD + col], w2 = W4xyz[2 * HD + col];
    const float bb = g ? 0.f : be1[col];
#pragma unroll
    for (int mt = 0; mt < 2; ++mt)
#pragma unroll
      for (int r = 0; r < 4; ++r) {
        const int row = mt * 16 + quad * 4 + r;     // local 0..31
        float dot = px[mt][r] * w0 + py[mt][r] * w1 + pz[mt][r] * w2;
        float v = acc[mt][nt][r] + (g ? -dot : dot) + bb;
        S[row * 136 + col] = (__bf16)v;
      }
  }
  __syncthreads();
  // coalesced store: 64 rows x 16 chunks of 16B, P and Q.
#pragma unroll
  for (int u = 0; u < 4; ++u) {
    const int idx = u * 256 + t;        // 0..1023
    const int row = idx >> 4, ch = idx & 15;
    const int node = base + row;
    if (node < NN) {
      *reinterpret_cast<uint4*>(PB + (size_t)node * HD + ch * 8) =
          *reinterpret_cast<const uint4*>(SP + row * 136 + ch * 8);
      *reinterpret_cast<uint4*>(QB + (size_t)node * HD + ch * 8) =
          *reinterpret_cast<const uint4*>(SQ + row * 136 + ch * 8);
    }
  }
}

// ---- edge kernel v12 = v7 body + SWAPPED-operand MFMA epilogue (r10).
// mfma16(x,y)[lane,reg] = sum_k X[(lane>>4)*4+reg][k] * Y[lane&15][k].
// Swapping operands (b first) makes each lane hold ONE edge row (cl) and
// FOUR CONSECUTIVE cols (quad*4+r) -> pack bf16x4 + one ds_write_b64.
// 32 scalar ds_write_b16 -> 8 vector writes per GEMM per thread (pure
// relabeling, same sums, same rounding). Targets the 33%-busy VALU pipe +
// LDS write pressure; rest of v7 untouched.
__global__ __launch_bounds__(512, 4) void edge_kernel(
    const __bf16* __restrict__ PB, const __bf16* __restrict__ QB,
    const __bf16* __restrict__ DSTb,
    const int* __restrict__ ROWS, const int* __restrict__ COLS,
    const float* __restrict__ w4d,      // We1_l row 259 (dist), 128 f32
    const __bf16* __restrict__ We2t, const __bf16* __restrict__ We3t,
    const float* __restrict__ be2, const float* __restrict__ be3,
    float* __restrict__ AGG)
{
  __shared__ __bf16 S1[EB * 136];               // 34816 B : m1, then m3
  __shared__ __bf16 S2[EB * 136];               // 34816 B : m2
  __shared__ float w4ds[HD], be2s[HD], be3s[HD];
  __shared__ int colS[EB];
  __shared__ unsigned long long bmaskS[EB / 64];
  const int t = threadIdx.x;

  // bijective XCD swizzle (m204 variant). nwg=6250.
  const int nwg = gridDim.x;
  const int q = nwg >> 3, r8 = nwg & 7;
  const int xcd = blockIdx.x & 7, idx8 = blockIdx.x >> 3;
  const int bswz = (xcd < r8 ? xcd * (q + 1) : r8 * (q + 1) + (xcd - r8) * q) + idx8;
  const int base = bswz * EB;

  if (t < HD) { w4ds[t] = w4d[t]; be2s[t] = be2[t]; be3s[t] = be3[t]; }
  if (t < EB) colS[t] = COLS[base + t];
  __syncthreads();                              // B0: w4ds/colS ready

  // segment-boundary bitmask: bit i of bmaskS[i>>6] = flush after row i.
  if (t < EB) {
    int d = (t == EB - 1) || (colS[t + 1] != colS[t]);
    unsigned long long bm = __ballot(d);
    if ((t & 63) == 0) bmaskS[t >> 6] = bm;
  }

  // ---- gather + combine -> m1 tile (S1). thread t: row t>>2, 4 chunks of 8.
  {
    const int i = t >> 2, cg = t & 3;
    const int p = base + i;
    const int c = colS[i];
    const int r = ROWS[p];
    const float dist = (float)DSTb[p];
    const __bf16* Prow = PB + (size_t)c * HD;
    const __bf16* Qrow = QB + (size_t)r * HD;
#pragma unroll
    for (int u = 0; u < 4; ++u) {
      const int ch = cg * 4 + u;
      bf16x8 pv = *reinterpret_cast<const bf16x8*>(Prow + ch * 8);
      bf16x8 qv = *reinterpret_cast<const bf16x8*>(Qrow + ch * 8);
      bf16x8 o;
#pragma unroll
      for (int j = 0; j < 8; ++j) {
        const int col = ch * 8 + j;
        float f = (float)pv[j] + (float)qv[j] + dist * w4ds[col];
        o[j] = (__bf16)fmaxf(f, 0.f);
      }
      *reinterpret_cast<bf16x8*>(S1 + i * 136 + ch * 8) = o;
    }
  }
  __syncthreads();                              // B1: m1 complete

  const int w = t >> 6, lane = t & 63;
  const int m_off = (w >> 2) * 64, n_off = (w & 3) * 32;   // wave: 64x32 tile
  const int arow = lane & 15, quad = lane >> 4, cl = lane & 15;

  f32x4 acc[4][2];
#pragma unroll
  for (int g = 0; g < 2; ++g) {
    const __bf16* Wt = g ? We3t : We2t;
    const float* bs = g ? be3s : be2s;
    const __bf16* Sin  = g ? S2 : S1;
    __bf16* Sout = g ? S1 : S2;

    // full-K b prefetch: 4 ks x 2 nt = 8 frags = 32 VGPR, one latency batch
    bf16x8 b[4][2];
#pragma unroll
    for (int ks = 0; ks < 4; ++ks)
#pragma unroll
      for (int nt = 0; nt < 2; ++nt)
        b[ks][nt] = *reinterpret_cast<const bf16x8*>(
            Wt + (size_t)(n_off + nt * 16 + arow) * HD + ks * 32 + quad * 8);

    zero_acc(acc);
#pragma unroll
    for (int ks = 0; ks < 4; ++ks) {
      const int k = ks * 32 + quad * 8;
      bf16x8 a[4];
#pragma unroll
      for (int mt = 0; mt < 4; ++mt)
        a[mt] = *reinterpret_cast<const bf16x8*>(Sin + (m_off + mt * 16 + arow) * 136 + k);
#pragma unroll
      for (int mt = 0; mt < 4; ++mt)
#pragma unroll
        for (int nt = 0; nt < 2; ++nt)
          acc[mt][nt] = mfma16(b[ks][nt], a[mt], acc[mt][nt]);   // SWAPPED
    }
    // swapped epilogue: lane -> edge row (cl), 4 consecutive cols (quad*4+r)
#pragma unroll
    for (int nt = 0; nt < 2; ++nt) {
      const int c0 = n_off + nt * 16 + quad * 4;
      float bv0 = bs[c0 + 0], bv1 = bs[c0 + 1], bv2 = bs[c0 + 2], bv3 = bs[c0 + 3];
#pragma unroll
      for (int mt = 0; mt < 4; ++mt) {
        const int row = m_off + mt * 16 + cl;
        float v0 = acc[mt][nt][0] + bv0;
        float v1 = acc[mt][nt][1] + bv1;
        float v2 = acc[mt][nt][2] + bv2;
        float v3 = acc[mt][nt][3] + bv3;
        if (!g) {
          v0 = fmaxf(v0, 0.f); v1 = fmaxf(v1, 0.f);
          v2 = fmaxf(v2, 0.f); v3 = fmaxf(v3, 0.f);
        }
        bf16x4 o;
        o[0] = (__bf16)v0; o[1] = (__bf16)v1; o[2] = (__bf16)v2; o[3] = (__bf16)v3;
        *reinterpret_cast<bf16x4*>(Sout + row * 136 + c0) = o;   // ds_write_b64
      }
    }
    __syncthreads();                            // B2 (m2 ready) / B3 (m3 ready)
  }

  // ---- block-level segmented reduce: col j, 32-row slices, bitmask flush.
  {
    const int j = t & 127, qtr = t >> 7;        // qtr in 0..3
    const int i0 = qtr * 32;
    unsigned int m = (unsigned int)(bmaskS[qtr >> 1] >> ((qtr & 1) * 32));
    m |= 0x80000000u;                           // force flush at slice end
    float s = 0.f;
    for (int r = 0; r < 32; ++r) {
      const int i = i0 + r;
      s += (float)S1[i * 136 + j];
      if ((m >> r) & 1u) {
        atomicAdd(&AGG[(size_t)colS[i] * HD + j], s);
        s = 0.f;
      }
    }
  }
}

// ---- node MLP + residual + LayerNorm + FUSED next-layer P/Q (r9, kept:
// neutral on time but fewer dispatches).
__global__ __launch_bounds__(256, 4) void node_kernel(
    const __bf16* __restrict__ HBin, float* __restrict__ AGG,
    const __bf16* __restrict__ Wn1t, const __bf16* __restrict__ Wn2t,
    const __bf16* __restrict__ Wn3t,
    const float* __restrict__ bn1, const float* __restrict__ bn2,
    const float* __restrict__ bn3,
    const float* __restrict__ lng, const float* __restrict__ lnb,
    const __bf16* __restrict__ Wtop_nxt, const __bf16* __restrict__ Wbot_nxt,
    const float* __restrict__ W4xyz_nxt, const float* __restrict__ be1_nxt,
    const float* __restrict__ pos,
    float* __restrict__ H32, __bf16* __restrict__ HBout,
    float* __restrict__ dout,
    __bf16* __restrict__ PBout, __bf16* __restrict__ QBout)
{
  __shared__ float SB[NM * 136];                 // 34.8 KB union
  __shared__ float ps[NM][2], psq[NM][2];
  __shared__ float mean_s[NM], rstd_s[NM];
  __bf16* B16 = reinterpret_cast<__bf16*>(SB);
  const int t = threadIdx.x;
  const int base = blockIdx.x * NM;

  {
    const int i0 = t >> 4, s = t & 15;
#pragma unroll
    for (int g = 0; g < NM / 16; ++g) {
      const int i = g * 16 + i0;
      const int node = base + i;
      uint4 v = make_uint4(0, 0, 0, 0);
      if (node < NN) v = *(reinterpret_cast<const uint4*>(HBin + (size_t)node * HD) + s);
      *reinterpret_cast<uint4*>(&B16[i * 264 + s * 8]) = v;
    }
  }
  for (int idx = t; idx < NM * 32; idx += 256) {
    const int i = idx >> 5, c4 = idx & 31;
    const int node = base + i;
    float4 v = make_float4(0.f, 0.f, 0.f, 0.f);
    if (node < NN) {
      float4* ap = reinterpret_cast<float4*>(AGG + (size_t)node * HD + c4 * 4);
      v = *ap;
      *ap = make_float4(0.f, 0.f, 0.f, 0.f);     // clear for next layer's edge pass
    }
    __bf16* d = &B16[i * 264 + HD + c4 * 4];
    d[0] = (__bf16)v.x; d[1] = (__bf16)v.y; d[2] = (__bf16)v.z; d[3] = (__bf16)v.w;
  }
  __syncthreads();

  const int w = t >> 6, lane = t & 63;
  const int m_off = (w >> 1) * 32, n_off = (w & 1) * 64;   // wave: 32x64 tile
  const int arow = lane & 15, quad = lane >> 4, cl = lane & 15;
  f32x4 acc[2][4];
  __bf16* reg0 = B16;                            // stride 136, [0, 17408)
  __bf16* reg1 = B16 + NM * 136;                 // stride 136, [17408, 34816)

  zero_acc(acc);
  gemm_chunk<2, 4, 4>(B16, 264, Wn1t, 256, 0,   m_off, n_off, lane, acc);
  gemm_chunk<2, 4, 4>(B16, 264, Wn1t, 256, 128, m_off, n_off, lane, acc);
  __syncthreads();                               // A reads done
  store_tile<2, 4, true>(reg0, 136, bn1, m_off, n_off, lane, acc);
  __syncthreads();
  zero_acc(acc);
  gemm_chunk<2, 4, 4>(reg0, 136, Wn2t, 128, 0, m_off, n_off, lane, acc);
  store_tile<2, 4, true>(reg1, 136, bn2, m_off, n_off, lane, acc);   // disjoint
  __syncthreads();
  zero_acc(acc);
  gemm_chunk<2, 4, 4>(reg1, 136, Wn3t, 128, 0, m_off, n_off, lane, acc);
  __syncthreads();                               // reg1 reads done

  {
#pragma unroll
    for (int nt = 0; nt < 4; ++nt) {
      const int col = n_off + nt * 16 + cl;
      const float bv = bn3[col];
#pragma unroll
      for (int mt = 0; mt < 2; ++mt)
#pragma unroll
        for (int r = 0; r < 4; ++r) {
          const int row = m_off + mt * 16 + quad * 4 + r;
          const int node = base + row;
          float hv = (node < NN) ? H32[(size_t)node * HD + col] : 0.f;
          SB[row * 136 + col] = hv + acc[mt][nt][r] + bv;
        }
    }
  }
  __syncthreads();
  if (t < 128) {
    const int r = t >> 1, hh = t & 1;
    float s = 0.f, sq = 0.f;
    for (int j = hh * 64; j < hh * 64 + 64; ++j) {
      float v = SB[r * 136 + j];
      s += v; sq += v * v;
    }
    ps[r][hh] = s; psq[r][hh] = sq;
  }
  __syncthreads();
  if (t < NM) {
    float s = ps[t][0] + ps[t][1];
    float sq = psq[t][0] + psq[t][1];
    float mean = s * (1.f / HD);
    float var = sq * (1.f / HD) - mean * mean;
    mean_s[t] = mean;
    rstd_s[t] = rsqrtf(var + 1e-5f);
  }
  __syncthreads();

  // LN apply: hold results in regs (SB reads must finish before B16 writes,
  // since B16 byte-aliases SB).
  float vreg[32];
#pragma unroll
  for (int u = 0; u < 32; ++u) {
    const int idx = u * 256 + t;
    const int r = idx >> 7, j = idx & 127;
    const int node = base + r;
    float v = 0.f;
    if (node < NN) {
      v = (SB[r * 136 + j] - mean_s[r]) * rstd_s[r] * lng[j] + lnb[j];
      H32[(size_t)node * HD + j] = v;
      if (dout) dout[(size_t)node * HD + j] = v;
    }
    vreg[u] = v;
  }
  __syncthreads();                               // all SB reads done
#pragma unroll
  for (int u = 0; u < 32; ++u) {
    const int idx = u * 256 + t;
    const int r = idx >> 7, j = idx & 127;
    B16[r * 136 + j] = (__bf16)vreg[u];          // bf16 h tile, stride 136
  }
  __syncthreads();                               // B16 ready

  if (HBout) {                                   // coalesced h store (skip last layer)
#pragma unroll
    for (int u = 0; u < 4; ++u) {
      const int idx = u * 256 + t;               // 64 rows x 16 chunks
      const int r = idx >> 4, ch = idx & 15;
      const int node = base + r;
      if (node < NN)
        *reinterpret_cast<uint4*>(HBout + (size_t)node * HD + ch * 8) =
            *reinterpret_cast<const uint4*>(B16 + r * 136 + ch * 8);
    }
  }

  // ---- fused next-layer P/Q (skip last layer)
  if (PBout) {
    __bf16* Sst = reg1;                          // second half, free now
    float px[4], py[4], pz[4];
#pragma unroll
    for (int r = 0; r < 4; ++r) {
      int row = base + w * 16 + quad * 4 + r;
      if (row >= NN) row = NN - 1;
      px[r] = pos[row * 3 + 0];
      py[r] = pos[row * 3 + 1];
      pz[r] = pos[row * 3 + 2];
    }
#pragma unroll
    for (int g = 0; g < 2; ++g) {
      const __bf16* Wt = g ? Wbot_nxt : Wtop_nxt;
      f32x4 pacc[8];
#pragma unroll
      for (int n = 0; n < 8; ++n) pacc[n] = f32x4{0.f, 0.f, 0.f, 0.f};
#pragma unroll
      for (int ks = 0; ks < 4; ++ks) {
        const int k = ks * 32 + quad * 8;
        bf16x8 a = *reinterpret_cast<const bf16x8*>(B16 + (w * 16 + arow) * 136 + k);
#pragma unroll
        for (int nt = 0; nt < 8; ++nt) {
          bf16x8 b = *reinterpret_cast<const bf16x8*>(
              Wt + (size_t)(nt * 16 + arow) * HD + k);
          pacc[nt] = mfma16(a, b, pacc[nt]);
        }
      }
#pragma unroll
      for (int nt = 0; nt < 8; ++nt) {
        const int col = nt * 16 + cl;
        const float w0 = W4xyz_nxt[col], w1 = W4xyz_nxt[HD + col],
                    w2 = W4xyz_nxt[2 * HD + col];
        const float bb = g ? 0.f : be1_nxt[col];
#pragma unroll
        for (int r = 0; r < 4; ++r) {
          const int lr = w * 16 + quad * 4 + r;  // local row 0..63
          float dot = px[r] * w0 + py[r] * w1 + pz[r] * w2;
          Sst[lr * 136 + col] = (__bf16)(pacc[nt][r] + (g ? -dot : dot) + bb);
        }
      }
      __syncthreads();                           // Sst tile complete
      __bf16* O = g ? QBout : PBout;
#pragma unroll
      for (int u = 0; u < 4; ++u) {
        const int idx = u * 256 + t;
        const int r = idx >> 4, ch = idx & 15;
        const int node = base + r;
        if (node < NN)
          *reinterpret_cast<uint4*>(O + (size_t)node * HD + ch * 8) =
              *reinterpret_cast<const uint4*>(Sst + r * 136 + ch * 8);
      }
      __syncthreads();                           // Sst reusable for g=1
    }
  }
}

extern "C" void kernel_launch(void* const* d_in, const int* in_sizes, int n_in,
                              void* d_out, int out_size, void* d_ws, size_t ws_size,
                              hipStream_t stream)
{
  const float* x    = (const float*)d_in[0];
  const float* pos  = (const float*)d_in[1];
  const int*   ei   = (const int*)d_in[2];
  const float* W_in = (const float*)d_in[3];
  const float* b_in = (const float*)d_in[4];
  const float* We1  = (const float*)d_in[5];
  const float* be1  = (const float*)d_in[6];
  const float* We2  = (const float*)d_in[7];
  const float* be2  = (const float*)d_in[8];
  const float* We3  = (const float*)d_in[9];
  const float* be3  = (const float*)d_in[10];
  const float* Wn1  = (const float*)d_in[11];
  const float* bn1  = (const float*)d_in[12];
  const float* Wn2  = (const float*)d_in[13];
  const float* bn2  = (const float*)d_in[14];
  const float* Wn3  = (const float*)d_in[15];
  const float* bn3  = (const float*)d_in[16];
  const float* lng  = (const float*)d_in[17];
  const float* lnb  = (const float*)d_in[18];
  float* out = (float*)d_out;

  char* ws = (char*)d_ws;
  size_t off = 0;
  auto alloc = [&](size_t bytes) -> char* {
    char* p = ws + off;
    off += (bytes + 255) & ~(size_t)255;
    return p;
  };
  __bf16* Wtopt = (__bf16*)alloc((size_t)NL * HD * HD * 2);
  __bf16* Wbott = (__bf16*)alloc((size_t)NL * HD * HD * 2);
  __bf16* We2t = (__bf16*)alloc((size_t)NL * HD * HD * 2);
  __bf16* We3t = (__bf16*)alloc((size_t)NL * HD * HD * 2);
  __bf16* Wn1t = (__bf16*)alloc((size_t)NL * HD * 256 * 2);
  __bf16* Wn2t = (__bf16*)alloc((size_t)NL * HD * HD * 2);
  __bf16* Wn3t = (__bf16*)alloc((size_t)NL * HD * HD * 2);
  __bf16* DSTb = (__bf16*)alloc((size_t)NE * 2);
  float*  H32  = (float*) alloc((size_t)NN * HD * 4);
  __bf16* HB   = (__bf16*)alloc((size_t)NN * HD * 2);
  __bf16* PB   = (__bf16*)alloc((size_t)NN * HD * 2);
  __bf16* QB   = (__bf16*)alloc((size_t)NN * HD * 2);
  float*  AGG  = (float*) alloc((size_t)NN * HD * 4);
  int*    CNT  = (int*)   alloc((size_t)NN * 4);
  int*    CUR  = (int*)   alloc((size_t)NN * 4);
  int*    ROWS = (int*)   alloc((size_t)NE * 4);
  int*    COLS = (int*)   alloc((size_t)NE * 4);

  hipMemsetAsync(CNT, 0, (size_t)NN * 4, stream);
  hipMemsetAsync(AGG, 0, (size_t)NN * HD * 4, stream);   // once; node_kernel re-zeroes
  prep_pqw<<<(NL * HD * HD + 255) / 256, 256, 0, stream>>>(We1, Wtopt, Wbott);
  prep_w<<<(NL * HD * HD + 255) / 256, 256, 0, stream>>>(We2, We2t, 128, 128);
  prep_w<<<(NL * HD * HD + 255) / 256, 256, 0, stream>>>(We3, We3t, 128, 128);
  prep_w<<<(NL * HD * 256 + 255) / 256, 256, 0, stream>>>(Wn1, Wn1t, 256, 256);
  prep_w<<<(NL * HD * HD + 255) / 256, 256, 0, stream>>>(Wn2, Wn2t, 128, 128);
  prep_w<<<(NL * HD * HD + 255) / 256, 256, 0, stream>>>(Wn3, Wn3t, 128, 128);
  h0_kernel<<<(NN * HD + 255) / 256, 256, 0, stream>>>(x, W_in, b_in, H32, HB);
  hist_kernel<<<(NE + 255) / 256, 256, 0, stream>>>(ei, CNT);
  scan_kernel<<<1, 1024, 0, stream>>>(CNT, CUR);
  scatter_kernel<<<(NE + 255) / 256, 256, 0, stream>>>(ei, CUR, pos, ROWS, COLS, DSTb);

  const int pq_blocks = (NN + 63) / 64;
  // layer 0 P/Q from h0 (layers 1-3 produced by node_kernel fusion)
  pq_kernel<<<pq_blocks, 256, 0, stream>>>(HB, pos,
      Wtopt, Wbott, We1 + 256 * HD, be1, PB, QB);

  for (int l = 0; l < NL; ++l) {
    const float* We1l = We1 + (size_t)l * 263 * HD;
    const bool last = (l == NL - 1);
    const float* We1n = We1 + (size_t)(l + 1) * 263 * HD;
    edge_kernel<<<NE / EB, 512, 0, stream>>>(PB, QB, DSTb, ROWS, COLS,
        We1l + 259 * HD,            // w4d (dist row)
        We2t + (size_t)l * HD * HD, We3t + (size_t)l * HD * HD,
        be2 + l * HD, be3 + l * HD, AGG);
    node_kernel<<<(NN + NM - 1) / NM, 256, 0, stream>>>(HB, AGG,
        Wn1t + (size_t)l * HD * 256, Wn2t + (size_t)l * HD * HD,
        Wn3t + (size_t)l * HD * HD,
        bn1 + l * HD, bn2 + l * HD, bn3 + l * HD,
        lng + l * HD, lnb + l * HD,
        last ? nullptr : Wtopt + (size_t)(l + 1) * HD * HD,
        last ? nullptr : Wbott + (size_t)(l + 1) * HD * HD,
        last ? nullptr : We1n + 256 * HD,
        last ? nullptr : be1 + (l + 1) * HD,
        pos,
        H32,
        last ? nullptr : HB,       // HBout (skip last layer)
        last ? out : nullptr,      // dout
        last ? nullptr : PB, last ? nullptr : QB);
  }
}

// Round 11
// 1223.453 us; speedup vs baseline: 1.0149x; 1.0149x over previous
//
#include <hip/hip_runtime.h>
#include <stdint.h>

#define NN 50000   // nodes
#define NE 800000  // edges
#define HD 128     // hidden
#define NL 4       // layers
#define NM 64      // nodes per block (node kernel)
#define EB 128     // edges per block (edge kernel)
#define SCH ((NN + 1023) / 1024)   // scan chunk per thread (49)

typedef __bf16 bf16x8 __attribute__((ext_vector_type(8)));
typedef __bf16 bf16x4 __attribute__((ext_vector_type(4)));
typedef float  f32x4  __attribute__((ext_vector_type(4)));

__device__ __forceinline__ f32x4 mfma16(bf16x8 a, bf16x8 b, f32x4 c) {
  return __builtin_amdgcn_mfma_f32_16x16x32_bf16(a, b, c, 0, 0, 0);
}

template<int MT, int NT>
__device__ __forceinline__ void zero_acc(f32x4 (&acc)[MT][NT]) {
#pragma unroll
  for (int i = 0; i < MT; ++i)
#pragma unroll
    for (int j = 0; j < NT; ++j) acc[i][j] = f32x4{0.f, 0.f, 0.f, 0.f};
}

// ---------------- generic MT/NT gemm chunk ----------------------------------
template<int MT, int NT, int KS>
__device__ __forceinline__ void gemm_chunk(const __bf16* A, int sa,
    const __bf16* __restrict__ Bt, int Krow, int k0,
    int m_off, int n_off, int lane, f32x4 (&acc)[MT][NT])
{
  const int arow = lane & 15;
  const int quad = lane >> 4;
  bf16x8 b[KS][NT];
#pragma unroll
  for (int ks = 0; ks < KS; ++ks)
#pragma unroll
    for (int nt = 0; nt < NT; ++nt)
      b[ks][nt] = *reinterpret_cast<const bf16x8*>(
          Bt + (size_t)(n_off + nt * 16 + arow) * Krow + k0 + ks * 32 + quad * 8);
#pragma unroll
  for (int ks = 0; ks < KS; ++ks) {
    const int k = k0 + ks * 32 + quad * 8;
    bf16x8 a[MT];
#pragma unroll
    for (int mt = 0; mt < MT; ++mt)
      a[mt] = *reinterpret_cast<const bf16x8*>(A + (m_off + mt * 16 + arow) * sa + k);
#pragma unroll
    for (int mt = 0; mt < MT; ++mt)
#pragma unroll
      for (int nt = 0; nt < NT; ++nt)
        acc[mt][nt] = mfma16(a[mt], b[ks][nt], acc[mt][nt]);
  }
}

// C/D layout (m89-verified): col = lane&15, row = (lane>>4)*4 + reg
template<int MT, int NT, bool RELU>
__device__ __forceinline__ void store_tile(__bf16* O, int so,
    const float* __restrict__ bias, int m_off, int n_off, int lane,
    f32x4 (&acc)[MT][NT])
{
  const int quad = lane >> 4;
  const int cl = lane & 15;
#pragma unroll
  for (int nt = 0; nt < NT; ++nt) {
    const int col = n_off + nt * 16 + cl;
    const float bv = bias[col];
#pragma unroll
    for (int mt = 0; mt < MT; ++mt)
#pragma unroll
      for (int r = 0; r < 4; ++r) {
        const int row = m_off + mt * 16 + quad * 4 + r;
        float v = acc[mt][nt][r] + bv;
        if (RELU) v = fmaxf(v, 0.f);
        O[row * so + col] = (__bf16)v;
      }
  }
}

// ---- prep_all (r11): all 7 weight transposes in ONE dispatch.
// Regions (each A = NL*HD*HD = 65536 elems): [0,A) pqw fold; [A,2A) We2t;
// [2A,3A) We3t; [3A,4A) Wn2t; [4A,5A) Wn3t; [5A, 5A+NL*HD*256) Wn1t.
__global__ void prep_all(const float* __restrict__ We1,
                         const float* __restrict__ We2, const float* __restrict__ We3,
                         const float* __restrict__ Wn1, const float* __restrict__ Wn2,
                         const float* __restrict__ Wn3,
                         __bf16* __restrict__ Wtopt, __bf16* __restrict__ Wbott,
                         __bf16* __restrict__ We2t, __bf16* __restrict__ We3t,
                         __bf16* __restrict__ Wn1t, __bf16* __restrict__ Wn2t,
                         __bf16* __restrict__ Wn3t) {
  const int A = NL * HD * HD;
  int idx = blockIdx.x * 256 + threadIdx.x;
  if (idx < A) {                                  // pqw fold
    int l = idx / (HD * HD);
    int rem = idx - l * HD * HD;
    int n = rem >> 7;
    int k = rem & 127;
    const float* W = We1 + (size_t)l * 263 * HD;
    float extra = (k >= 3 && k < 6) ? W[(260 + k - 3) * HD + n] : 0.f;
    Wtopt[idx] = (__bf16)(W[k * HD + n] + extra);
    Wbott[idx] = (__bf16)(W[(128 + k) * HD + n] - extra);
    return;
  }
  if (idx < 5 * A) {                              // 128x128 transposes
    int region = (idx - A) / A;                   // 0..3
    int i = (idx - A) - region * A;
    const float* W = (region == 0) ? We2 : (region == 1) ? We3
                   : (region == 2) ? Wn2 : Wn3;
    __bf16* Wt = (region == 0) ? We2t : (region == 1) ? We3t
               : (region == 2) ? Wn2t : Wn3t;
    int l = i / (HD * HD);
    int rem = i - l * HD * HD;
    int n = rem >> 7;
    int k = rem & 127;
    Wt[i] = (__bf16)W[((size_t)l * HD + k) * HD + n];
    return;
  }
  int i = idx - 5 * A;                            // Wn1t : K=256
  if (i >= NL * HD * 256) return;
  int l = i / (HD * 256);
  int rem = i - l * HD * 256;
  int n = rem >> 8;
  int k = rem & 255;
  Wn1t[i] = (__bf16)Wn1[((size_t)l * 256 + k) * HD + n];
}

// ---- h0 = x @ W_in + b_in
__global__ void h0_kernel(const float* __restrict__ x, const float* __restrict__ W,
                          const float* __restrict__ b, float* __restrict__ H32,
                          __bf16* __restrict__ HB) {
  int idx = blockIdx.x * 256 + threadIdx.x;
  if (idx >= NN * HD) return;
  int node = idx >> 7, j = idx & 127;
  const float* xr = x + node * 16;
  float s = b[j];
#pragma unroll
  for (int k = 0; k < 16; ++k) s += xr[k] * W[k * HD + j];
  H32[idx] = s;
  HB[idx] = (__bf16)s;
}

// ---- CSR build (counting sort of edges by col)
__global__ void hist_kernel(const int* __restrict__ ei, int* __restrict__ cnt) {
  int e = blockIdx.x * 256 + threadIdx.x;
  if (e < NE) atomicAdd(&cnt[ei[NE + e]], 1);
}

// ---- chunked single-block scan: thread t owns cnt[t*SCH .. t*SCH+SCH-1].
__global__ void scan_kernel(const int* __restrict__ cnt, int* __restrict__ cur) {
  __shared__ int wsum[16];
  const int t = threadIdx.x;            // 1024 threads
  const int lane = t & 63, wid = t >> 6;
  const int base = t * SCH;
  int s = 0;
  for (int k = 0; k < SCH; ++k) {
    int i = base + k;
    if (i < NN) s += cnt[i];
  }
  int incl = s;
#pragma unroll
  for (int off = 1; off < 64; off <<= 1) {
    int u = __shfl_up(incl, off, 64);
    if (lane >= off) incl += u;
  }
  if (lane == 63) wsum[wid] = incl;
  __syncthreads();
  int woff = 0;
  for (int k = 0; k < wid; ++k) woff += wsum[k];
  int run = woff + incl - s;            // exclusive prefix of this chunk
  for (int k = 0; k < SCH; ++k) {
    int i = base + k;
    if (i < NN) { cur[i] = run; run += cnt[i]; }
  }
}

// ---- scatter + fused dist
__global__ void scatter_kernel(const int* __restrict__ ei, int* __restrict__ cur,
                               const float* __restrict__ pos,
                               int* __restrict__ ROWS, int* __restrict__ COLS,
                               __bf16* __restrict__ DSTb) {
  int e = blockIdx.x * 256 + threadIdx.x;
  if (e < NE) {
    int r = ei[e], c = ei[NE + e];
    int p = atomicAdd(&cur[c], 1);
    ROWS[p] = r;
    COLS[p] = c;
    float dx = pos[c * 3 + 0] - pos[r * 3 + 0];
    float dy = pos[c * 3 + 1] - pos[r * 3 + 1];
    float dz = pos[c * 3 + 2] - pos[r * 3 + 2];
    DSTb[p] = (__bf16)sqrtf(dx * dx + dy * dy + dz * dz);
  }
}

// ---- P/Q kernel v3 (layer 0 ONLY; layers 1-3 fused into node_kernel).
__global__ __launch_bounds__(256, 4) void pq_kernel(
    const __bf16* __restrict__ HB, const float* __restrict__ pos,
    const __bf16* __restrict__ Wtopt, const __bf16* __restrict__ Wbott,
    const float* __restrict__ W4xyz,   // We1_l rows 256..258 : [3][128]
    const float* __restrict__ be1,
    __bf16* __restrict__ PB, __bf16* __restrict__ QB)
{
  __shared__ __bf16 SP[64 * 136];               // 17408 B
  __shared__ __bf16 SQ[64 * 136];               // 17408 B
  const int t = threadIdx.x;
  const int w = t >> 6, lane = t & 63;
  const int g = w & 1;                  // 0 -> P, 1 -> Q
  const int half = w >> 1;              // row half (0/1)
  const int base = blockIdx.x * 64;
  const int rbase = base + half * 32;
  const int arow = lane & 15, quad = lane >> 4, cl = lane & 15;

  const __bf16* Wt = g ? Wbott : Wtopt;
  __bf16* S = (g ? SQ : SP) + half * 32 * 136;

  f32x4 acc[2][8];
  zero_acc(acc);
#pragma unroll
  for (int ks = 0; ks < 4; ++ks) {
    const int k = ks * 32 + quad * 8;
    bf16x8 b[8];
#pragma unroll
    for (int nt = 0; nt < 8; ++nt)
      b[nt] = *reinterpret_cast<const bf16x8*>(Wt + (size_t)(nt * 16 + arow) * HD + k);
    bf16x8 a[2];
#pragma unroll
    for (int mt = 0; mt < 2; ++mt) {
      int row = rbase + mt * 16 + arow;
      if (row >= NN) row = NN - 1;       // clamp (stores guarded)
      a[mt] = *reinterpret_cast<const bf16x8*>(HB + (size_t)row * HD + k);
    }
#pragma unroll
    for (int mt = 0; mt < 2; ++mt)
#pragma unroll
      for (int nt = 0; nt < 8; ++nt)
        acc[mt][nt] = mfma16(a[mt], b[nt], acc[mt][nt]);
  }
  float px[2][4], py[2][4], pz[2][4];
#pragma unroll
  for (int mt = 0; mt < 2; ++mt)
#pragma unroll
    for (int r = 0; r < 4; ++r) {
      int row = rbase + mt * 16 + quad * 4 + r;
      if (row >= NN) row = NN - 1;
      px[mt][r] = pos[row * 3 + 0];
      py[mt][r] = pos[row * 3 + 1];
      pz[mt][r] = pos[row * 3 + 2];
    }
#pragma unroll
  for (int nt = 0; nt < 8; ++nt) {
    const int col = nt * 16 + cl;
    const float w0 = W4xyz[col], w1 = W4xyz[HD + col], w2 = W4xyz[2 * HD + col];
    const float bb = g ? 0.f : be1[col];
#pragma unroll
    for (int mt = 0; mt < 2; ++mt)
#pragma unroll
      for (int r = 0; r < 4; ++r) {
        const int row = mt * 16 + quad * 4 + r;     // local 0..31
        float dot = px[mt][r] * w0 + py[mt][r] * w1 + pz[mt][r] * w2;
        float v = acc[mt][nt][r] + (g ? -dot : dot) + bb;
        S[row * 136 + col] = (__bf16)v;
      }
  }
  __syncthreads();
  // coalesced store: 64 rows x 16 chunks of 16B, P and Q.
#pragma unroll
  for (int u = 0; u < 4; ++u) {
    const int idx = u * 256 + t;        // 0..1023
    const int row = idx >> 4, ch = idx & 15;
    const int node = base + row;
    if (node < NN) {
      *reinterpret_cast<uint4*>(PB + (size_t)node * HD + ch * 8) =
          *reinterpret_cast<const uint4*>(SP + row * 136 + ch * 8);
      *reinterpret_cast<uint4*>(QB + (size_t)node * HD + ch * 8) =
          *reinterpret_cast<const uint4*>(SQ + row * 136 + ch * 8);
    }
  }
}

// ---- edge kernel v12 (kept from r10; v7 body + swapped-operand epilogue).
// 8 probes establish this as the structural plateau: occupancy hard-capped at
// 16 waves/CU (84 regs > 64-reg threshold for 6 waves/SIMD), all pipes <43%.
__global__ __launch_bounds__(512, 4) void edge_kernel(
    const __bf16* __restrict__ PB, const __bf16* __restrict__ QB,
    const __bf16* __restrict__ DSTb,
    const int* __restrict__ ROWS, const int* __restrict__ COLS,
    const float* __restrict__ w4d,      // We1_l row 259 (dist), 128 f32
    const __bf16* __restrict__ We2t, const __bf16* __restrict__ We3t,
    const float* __restrict__ be2, const float* __restrict__ be3,
    float* __restrict__ AGG)
{
  __shared__ __bf16 S1[EB * 136];               // 34816 B : m1, then m3
  __shared__ __bf16 S2[EB * 136];               // 34816 B : m2
  __shared__ float w4ds[HD], be2s[HD], be3s[HD];
  __shared__ int colS[EB];
  __shared__ unsigned long long bmaskS[EB / 64];
  const int t = threadIdx.x;

  // bijective XCD swizzle (m204 variant). nwg=6250.
  const int nwg = gridDim.x;
  const int q = nwg >> 3, r8 = nwg & 7;
  const int xcd = blockIdx.x & 7, idx8 = blockIdx.x >> 3;
  const int bswz = (xcd < r8 ? xcd * (q + 1) : r8 * (q + 1) + (xcd - r8) * q) + idx8;
  const int base = bswz * EB;

  if (t < HD) { w4ds[t] = w4d[t]; be2s[t] = be2[t]; be3s[t] = be3[t]; }
  if (t < EB) colS[t] = COLS[base + t];
  __syncthreads();                              // B0: w4ds/colS ready

  // segment-boundary bitmask: bit i of bmaskS[i>>6] = flush after row i.
  if (t < EB) {
    int d = (t == EB - 1) || (colS[t + 1] != colS[t]);
    unsigned long long bm = __ballot(d);
    if ((t & 63) == 0) bmaskS[t >> 6] = bm;
  }

  // ---- gather + combine -> m1 tile (S1). thread t: row t>>2, 4 chunks of 8.
  {
    const int i = t >> 2, cg = t & 3;
    const int p = base + i;
    const int c = colS[i];
    const int r = ROWS[p];
    const float dist = (float)DSTb[p];
    const __bf16* Prow = PB + (size_t)c * HD;
    const __bf16* Qrow = QB + (size_t)r * HD;
#pragma unroll
    for (int u = 0; u < 4; ++u) {
      const int ch = cg * 4 + u;
      bf16x8 pv = *reinterpret_cast<const bf16x8*>(Prow + ch * 8);
      bf16x8 qv = *reinterpret_cast<const bf16x8*>(Qrow + ch * 8);
      bf16x8 o;
#pragma unroll
      for (int j = 0; j < 8; ++j) {
        const int col = ch * 8 + j;
        float f = (float)pv[j] + (float)qv[j] + dist * w4ds[col];
        o[j] = (__bf16)fmaxf(f, 0.f);
      }
      *reinterpret_cast<bf16x8*>(S1 + i * 136 + ch * 8) = o;
    }
  }
  __syncthreads();                              // B1: m1 complete

  const int w = t >> 6, lane = t & 63;
  const int m_off = (w >> 2) * 64, n_off = (w & 3) * 32;   // wave: 64x32 tile
  const int arow = lane & 15, quad = lane >> 4, cl = lane & 15;

  f32x4 acc[4][2];
#pragma unroll
  for (int g = 0; g < 2; ++g) {
    const __bf16* Wt = g ? We3t : We2t;
    const float* bs = g ? be3s : be2s;
    const __bf16* Sin  = g ? S2 : S1;
    __bf16* Sout = g ? S1 : S2;

    // full-K b prefetch: 4 ks x 2 nt = 8 frags = 32 VGPR, one latency batch
    bf16x8 b[4][2];
#pragma unroll
    for (int ks = 0; ks < 4; ++ks)
#pragma unroll
      for (int nt = 0; nt < 2; ++nt)
        b[ks][nt] = *reinterpret_cast<const bf16x8*>(
            Wt + (size_t)(n_off + nt * 16 + arow) * HD + ks * 32 + quad * 8);

    zero_acc(acc);
#pragma unroll
    for (int ks = 0; ks < 4; ++ks) {
      const int k = ks * 32 + quad * 8;
      bf16x8 a[4];
#pragma unroll
      for (int mt = 0; mt < 4; ++mt)
        a[mt] = *reinterpret_cast<const bf16x8*>(Sin + (m_off + mt * 16 + arow) * 136 + k);
#pragma unroll
      for (int mt = 0; mt < 4; ++mt)
#pragma unroll
        for (int nt = 0; nt < 2; ++nt)
          acc[mt][nt] = mfma16(b[ks][nt], a[mt], acc[mt][nt]);   // SWAPPED
    }
    // swapped epilogue: lane -> edge row (cl), 4 consecutive cols (quad*4+r)
#pragma unroll
    for (int nt = 0; nt < 2; ++nt) {
      const int c0 = n_off + nt * 16 + quad * 4;
      float bv0 = bs[c0 + 0], bv1 = bs[c0 + 1], bv2 = bs[c0 + 2], bv3 = bs[c0 + 3];
#pragma unroll
      for (int mt = 0; mt < 4; ++mt) {
        const int row = m_off + mt * 16 + cl;
        float v0 = acc[mt][nt][0] + bv0;
        float v1 = acc[mt][nt][1] + bv1;
        float v2 = acc[mt][nt][2] + bv2;
        float v3 = acc[mt][nt][3] + bv3;
        if (!g) {
          v0 = fmaxf(v0, 0.f); v1 = fmaxf(v1, 0.f);
          v2 = fmaxf(v2, 0.f); v3 = fmaxf(v3, 0.f);
        }
        bf16x4 o;
        o[0] = (__bf16)v0; o[1] = (__bf16)v1; o[2] = (__bf16)v2; o[3] = (__bf16)v3;
        *reinterpret_cast<bf16x4*>(Sout + row * 136 + c0) = o;   // ds_write_b64
      }
    }
    __syncthreads();                            // B2 (m2 ready) / B3 (m3 ready)
  }

  // ---- block-level segmented reduce: col j, 32-row slices, bitmask flush.
  {
    const int j = t & 127, qtr = t >> 7;        // qtr in 0..3
    const int i0 = qtr * 32;
    unsigned int m = (unsigned int)(bmaskS[qtr >> 1] >> ((qtr & 1) * 32));
    m |= 0x80000000u;                           // force flush at slice end
    float s = 0.f;
    for (int r = 0; r < 32; ++r) {
      const int i = i0 + r;
      s += (float)S1[i * 136 + j];
      if ((m >> r) & 1u) {
        atomicAdd(&AGG[(size_t)colS[i] * HD + j], s);
        s = 0.f;
      }
    }
  }
}

// ---- node MLP + residual + LayerNorm + FUSED next-layer P/Q.
// r11: last layer (dout != null) skips the dead H32 store (25.6MB) and the
// AGG re-zero (25.6MB RMW) — nothing reads either after the final layer.
__global__ __launch_bounds__(256, 4) void node_kernel(
    const __bf16* __restrict__ HBin, float* __restrict__ AGG,
    const __bf16* __restrict__ Wn1t, const __bf16* __restrict__ Wn2t,
    const __bf16* __restrict__ Wn3t,
    const float* __restrict__ bn1, const float* __restrict__ bn2,
    const float* __restrict__ bn3,
    const float* __restrict__ lng, const float* __restrict__ lnb,
    const __bf16* __restrict__ Wtop_nxt, const __bf16* __restrict__ Wbot_nxt,
    const float* __restrict__ W4xyz_nxt, const float* __restrict__ be1_nxt,
    const float* __restrict__ pos,
    float* __restrict__ H32, __bf16* __restrict__ HBout,
    float* __restrict__ dout,
    __bf16* __restrict__ PBout, __bf16* __restrict__ QBout)
{
  __shared__ float SB[NM * 136];                 // 34.8 KB union
  __shared__ float ps[NM][2], psq[NM][2];
  __shared__ float mean_s[NM], rstd_s[NM];
  __bf16* B16 = reinterpret_cast<__bf16*>(SB);
  const int t = threadIdx.x;
  const int base = blockIdx.x * NM;

  {
    const int i0 = t >> 4, s = t & 15;
#pragma unroll
    for (int g = 0; g < NM / 16; ++g) {
      const int i = g * 16 + i0;
      const int node = base + i;
      uint4 v = make_uint4(0, 0, 0, 0);
      if (node < NN) v = *(reinterpret_cast<const uint4*>(HBin + (size_t)node * HD) + s);
      *reinterpret_cast<uint4*>(&B16[i * 264 + s * 8]) = v;
    }
  }
  for (int idx = t; idx < NM * 32; idx += 256) {
    const int i = idx >> 5, c4 = idx & 31;
    const int node = base + i;
    float4 v = make_float4(0.f, 0.f, 0.f, 0.f);
    if (node < NN) {
      float4* ap = reinterpret_cast<float4*>(AGG + (size_t)node * HD + c4 * 4);
      v = *ap;
      if (!dout) *ap = make_float4(0.f, 0.f, 0.f, 0.f);  // skip on last layer
    }
    __bf16* d = &B16[i * 264 + HD + c4 * 4];
    d[0] = (__bf16)v.x; d[1] = (__bf16)v.y; d[2] = (__bf16)v.z; d[3] = (__bf16)v.w;
  }
  __syncthreads();

  const int w = t >> 6, lane = t & 63;
  const int m_off = (w >> 1) * 32, n_off = (w & 1) * 64;   // wave: 32x64 tile
  const int arow = lane & 15, quad = lane >> 4, cl = lane & 15;
  f32x4 acc[2][4];
  __bf16* reg0 = B16;                            // stride 136, [0, 17408)
  __bf16* reg1 = B16 + NM * 136;                 // stride 136, [17408, 34816)

  zero_acc(acc);
  gemm_chunk<2, 4, 4>(B16, 264, Wn1t, 256, 0,   m_off, n_off, lane, acc);
  gemm_chunk<2, 4, 4>(B16, 264, Wn1t, 256, 128, m_off, n_off, lane, acc);
  __syncthreads();                               // A reads done
  store_tile<2, 4, true>(reg0, 136, bn1, m_off, n_off, lane, acc);
  __syncthreads();
  zero_acc(acc);
  gemm_chunk<2, 4, 4>(reg0, 136, Wn2t, 128, 0, m_off, n_off, lane, acc);
  store_tile<2, 4, true>(reg1, 136, bn2, m_off, n_off, lane, acc);   // disjoint
  __syncthreads();
  zero_acc(acc);
  gemm_chunk<2, 4, 4>(reg1, 136, Wn3t, 128, 0, m_off, n_off, lane, acc);
  __syncthreads();                               // reg1 reads done

  {
#pragma unroll
    for (int nt = 0; nt < 4; ++nt) {
      const int col = n_off + nt * 16 + cl;
      const float bv = bn3[col];
#pragma unroll
      for (int mt = 0; mt < 2; ++mt)
#pragma unroll
        for (int r = 0; r < 4; ++r) {
          const int row = m_off + mt * 16 + quad * 4 + r;
          const int node = base + row;
          float hv = (node < NN) ? H32[(size_t)node * HD + col] : 0.f;
          SB[row * 136 + col] = hv + acc[mt][nt][r] + bv;
        }
    }
  }
  __syncthreads();
  if (t < 128) {
    const int r = t >> 1, hh = t & 1;
    float s = 0.f, sq = 0.f;
    for (int j = hh * 64; j < hh * 64 + 64; ++j) {
      float v = SB[r * 136 + j];
      s += v; sq += v * v;
    }
    ps[r][hh] = s; psq[r][hh] = sq;
  }
  __syncthreads();
  if (t < NM) {
    float s = ps[t][0] + ps[t][1];
    float sq = psq[t][0] + psq[t][1];
    float mean = s * (1.f / HD);
    float var = sq * (1.f / HD) - mean * mean;
    mean_s[t] = mean;
    rstd_s[t] = rsqrtf(var + 1e-5f);
  }
  __syncthreads();

  // LN apply: hold results in regs (SB reads must finish before B16 writes,
  // since B16 byte-aliases SB). Last layer writes dout ONLY (H32 dead after).
  float vreg[32];
#pragma unroll
  for (int u = 0; u < 32; ++u) {
    const int idx = u * 256 + t;
    const int r = idx >> 7, j = idx & 127;
    const int node = base + r;
    float v = 0.f;
    if (node < NN) {
      v = (SB[r * 136 + j] - mean_s[r]) * rstd_s[r] * lng[j] + lnb[j];
      if (dout) dout[(size_t)node * HD + j] = v;
      else      H32[(size_t)node * HD + j] = v;
    }
    vreg[u] = v;
  }
  __syncthreads();                               // all SB reads done
#pragma unroll
  for (int u = 0; u < 32; ++u) {
    const int idx = u * 256 + t;
    const int r = idx >> 7, j = idx & 127;
    B16[r * 136 + j] = (__bf16)vreg[u];          // bf16 h tile, stride 136
  }
  __syncthreads();                               // B16 ready

  if (HBout) {                                   // coalesced h store (skip last layer)
#pragma unroll
    for (int u = 0; u < 4; ++u) {
      const int idx = u * 256 + t;               // 64 rows x 16 chunks
      const int r = idx >> 4, ch = idx & 15;
      const int node = base + r;
      if (node < NN)
        *reinterpret_cast<uint4*>(HBout + (size_t)node * HD + ch * 8) =
            *reinterpret_cast<const uint4*>(B16 + r * 136 + ch * 8);
    }
  }

  // ---- fused next-layer P/Q (skip last layer)
  if (PBout) {
    __bf16* Sst = reg1;                          // second half, free now
    float px[4], py[4], pz[4];
#pragma unroll
    for (int r = 0; r < 4; ++r) {
      int row = base + w * 16 + quad * 4 + r;
      if (row >= NN) row = NN - 1;
      px[r] = pos[row * 3 + 0];
      py[r] = pos[row * 3 + 1];
      pz[r] = pos[row * 3 + 2];
    }
#pragma unroll
    for (int g = 0; g < 2; ++g) {
      const __bf16* Wt = g ? Wbot_nxt : Wtop_nxt;
      f32x4 pacc[8];
#pragma unroll
      for (int n = 0; n < 8; ++n) pacc[n] = f32x4{0.f, 0.f, 0.f, 0.f};
#pragma unroll
      for (int ks = 0; ks < 4; ++ks) {
        const int k = ks * 32 + quad * 8;
        bf16x8 a = *reinterpret_cast<const bf16x8*>(B16 + (w * 16 + arow) * 136 + k);
#pragma unroll
        for (int nt = 0; nt < 8; ++nt) {
          bf16x8 b = *reinterpret_cast<const bf16x8*>(
              Wt + (size_t)(nt * 16 + arow) * HD + k);
          pacc[nt] = mfma16(a, b, pacc[nt]);
        }
      }
#pragma unroll
      for (int nt = 0; nt < 8; ++nt) {
        const int col = nt * 16 + cl;
        const float w0 = W4xyz_nxt[col], w1 = W4xyz_nxt[HD + col],
                    w2 = W4xyz_nxt[2 * HD + col];
        const float bb = g ? 0.f : be1_nxt[col];
#pragma unroll
        for (int r = 0; r < 4; ++r) {
          const int lr = w * 16 + quad * 4 + r;  // local row 0..63
          float dot = px[r] * w0 + py[r] * w1 + pz[r] * w2;
          Sst[lr * 136 + col] = (__bf16)(pacc[nt][r] + (g ? -dot : dot) + bb);
        }
      }
      __syncthreads();                           // Sst tile complete
      __bf16* O = g ? QBout : PBout;
#pragma unroll
      for (int u = 0; u < 4; ++u) {
        const int idx = u * 256 + t;
        const int r = idx >> 4, ch = idx & 15;
        const int node = base + r;
        if (node < NN)
          *reinterpret_cast<uint4*>(O + (size_t)node * HD + ch * 8) =
              *reinterpret_cast<const uint4*>(Sst + r * 136 + ch * 8);
      }
      __syncthreads();                           // Sst reusable for g=1
    }
  }
}

extern "C" void kernel_launch(void* const* d_in, const int* in_sizes, int n_in,
                              void* d_out, int out_size, void* d_ws, size_t ws_size,
                              hipStream_t stream)
{
  const float* x    = (const float*)d_in[0];
  const float* pos  = (const float*)d_in[1];
  const int*   ei   = (const int*)d_in[2];
  const float* W_in = (const float*)d_in[3];
  const float* b_in = (const float*)d_in[4];
  const float* We1  = (const float*)d_in[5];
  const float* be1  = (const float*)d_in[6];
  const float* We2  = (const float*)d_in[7];
  const float* be2  = (const float*)d_in[8];
  const float* We3  = (const float*)d_in[9];
  const float* be3  = (const float*)d_in[10];
  const float* Wn1  = (const float*)d_in[11];
  const float* bn1  = (const float*)d_in[12];
  const float* Wn2  = (const float*)d_in[13];
  const float* bn2  = (const float*)d_in[14];
  const float* Wn3  = (const float*)d_in[15];
  const float* bn3  = (const float*)d_in[16];
  const float* lng  = (const float*)d_in[17];
  const float* lnb  = (const float*)d_in[18];
  float* out = (float*)d_out;

  char* ws = (char*)d_ws;
  size_t off = 0;
  auto alloc = [&](size_t bytes) -> char* {
    char* p = ws + off;
    off += (bytes + 255) & ~(size_t)255;
    return p;
  };
  __bf16* Wtopt = (__bf16*)alloc((size_t)NL * HD * HD * 2);
  __bf16* Wbott = (__bf16*)alloc((size_t)NL * HD * HD * 2);
  __bf16* We2t = (__bf16*)alloc((size_t)NL * HD * HD * 2);
  __bf16* We3t = (__bf16*)alloc((size_t)NL * HD * HD * 2);
  __bf16* Wn1t = (__bf16*)alloc((size_t)NL * HD * 256 * 2);
  __bf16* Wn2t = (__bf16*)alloc((size_t)NL * HD * HD * 2);
  __bf16* Wn3t = (__bf16*)alloc((size_t)NL * HD * HD * 2);
  __bf16* DSTb = (__bf16*)alloc((size_t)NE * 2);
  float*  H32  = (float*) alloc((size_t)NN * HD * 4);
  __bf16* HB   = (__bf16*)alloc((size_t)NN * HD * 2);
  __bf16* PB   = (__bf16*)alloc((size_t)NN * HD * 2);
  __bf16* QB   = (__bf16*)alloc((size_t)NN * HD * 2);
  float*  AGG  = (float*) alloc((size_t)NN * HD * 4);
  int*    CNT  = (int*)   alloc((size_t)NN * 4);
  int*    CUR  = (int*)   alloc((size_t)NN * 4);
  int*    ROWS = (int*)   alloc((size_t)NE * 4);
  int*    COLS = (int*)   alloc((size_t)NE * 4);

  hipMemsetAsync(CNT, 0, (size_t)NN * 4, stream);
  hipMemsetAsync(AGG, 0, (size_t)NN * HD * 4, stream);   // once; node re-zeroes (layers 0-2)
  {
    const int A = NL * HD * HD;
    const int total = 5 * A + NL * HD * 256;    // 458752
    prep_all<<<(total + 255) / 256, 256, 0, stream>>>(We1, We2, We3, Wn1, Wn2, Wn3,
        Wtopt, Wbott, We2t, We3t, Wn1t, Wn2t, Wn3t);
  }
  h0_kernel<<<(NN * HD + 255) / 256, 256, 0, stream>>>(x, W_in, b_in, H32, HB);
  hist_kernel<<<(NE + 255) / 256, 256, 0, stream>>>(ei, CNT);
  scan_kernel<<<1, 1024, 0, stream>>>(CNT, CUR);
  scatter_kernel<<<(NE + 255) / 256, 256, 0, stream>>>(ei, CUR, pos, ROWS, COLS, DSTb);

  const int pq_blocks = (NN + 63) / 64;
  // layer 0 P/Q from h0 (layers 1-3 produced by node_kernel fusion)
  pq_kernel<<<pq_blocks, 256, 0, stream>>>(HB, pos,
      Wtopt, Wbott, We1 + 256 * HD, be1, PB, QB);

  for (int l = 0; l < NL; ++l) {
    const float* We1l = We1 + (size_t)l * 263 * HD;
    const bool last = (l == NL - 1);
    const float* We1n = We1 + (size_t)(l + 1) * 263 * HD;
    edge_kernel<<<NE / EB, 512, 0, stream>>>(PB, QB, DSTb, ROWS, COLS,
        We1l + 259 * HD,            // w4d (dist row)
        We2t + (size_t)l * HD * HD, We3t + (size_t)l * HD * HD,
        be2 + l * HD, be3 + l * HD, AGG);
    node_kernel<<<(NN + NM - 1) / NM, 256, 0, stream>>>(HB, AGG,
        Wn1t + (size_t)l * HD * 256, Wn2t + (size_t)l * HD * HD,
        Wn3t + (size_t)l * HD * HD,
        bn1 + l * HD, bn2 + l * HD, bn3 + l * HD,
        lng + l * HD, lnb + l * HD,
        last ? nullptr : Wtopt + (size_t)(l + 1) * HD * HD,
        last ? nullptr : Wbott + (size_t)(l + 1) * HD * HD,
        last ? nullptr : We1n + 256 * HD,
        last ? nullptr : be1 + (l + 1) * HD,
        pos,
        H32,
        last ? nullptr : HB,       // HBout (skip last layer)
        last ? out : nullptr,      // dout
        last ? nullptr : PB, last ? nullptr : QB);
  }
}